// Round 6
// baseline (443.276 us; speedup 1.0000x reference)
//
#include <hip/hip_runtime.h>

#define B_ 256
#define T_ 512
#define F_ 64
#define U_ 128
#define PSTRIDE 132

typedef _Float16 h2v __attribute__((ext_vector_type(2)));
union U32H2 { unsigned u; h2v h; };

__device__ __forceinline__ float fdot2(unsigned a, unsigned b, float c) {
  U32H2 x, y; x.u = a; y.u = b;
  return __builtin_amdgcn_fdot2(x.h, y.h, c, false);
}

__device__ __forceinline__ unsigned packh2(float a, float b) {
  U32H2 r; r.h[0] = (_Float16)a; r.h[1] = (_Float16)b; return r.u;
}

__device__ __forceinline__ float fast_sig(float x) {
  return __builtin_amdgcn_rcpf(1.0f + __expf(-x));
}
__device__ __forceinline__ float fast_tanh(float x) {
  return fmaf(-2.0f, __builtin_amdgcn_rcpf(1.0f + __expf(2.0f * x)), 1.0f);
}

__global__ __launch_bounds__(512) void grud_kernel(
    const float* __restrict__ x, const float* __restrict__ m,
    const float* __restrict__ delta_t,
    const float* __restrict__ Wz, const float* __restrict__ Uz, const float* __restrict__ bz,
    const float* __restrict__ Wr, const float* __restrict__ Ur, const float* __restrict__ br,
    const float* __restrict__ Wh, const float* __restrict__ Uh, const float* __restrict__ bh,
    const float* __restrict__ gxd, const float* __restrict__ ghd,
    const float* __restrict__ mi,
    float* __restrict__ out)
{
  const int tid  = threadIdx.x;
  const int b    = blockIdx.x;
  const int team = tid >> 7;    // 0=Z 1=R 2=H 3=X (wave-uniform: 2 waves/team)
  const int uu   = tid & 127;   // owned output column

  // big pool for fp32 weight staging (pre-loop); re-carved for the step loop.
  __shared__ float s_mem[U_ * PSTRIDE];      // 67.6 KB
  float*  const s_pool = s_mem;
  float*  const s_zf   = s_mem;              // [128] z values (fp32)
  float*  const s_ax   = s_mem + 128;        // [2][3][128] x-projections (+bias)
  ushort* const s_x16h = (ushort*)(s_mem + 896);  // [32][64] decayed x, fp16
  __shared__ __align__(16) ushort s_hd16[U_];     // h_dec fp16
  __shared__ __align__(16) ushort s_rh16[U_];     // r*h_dec fp16
  __shared__ float s_dt[40];

  // One shared-name register array: Z/R/H use [0..64), X uses [0..96).
  unsigned wcol[96];

#define STAGE_MAT(SRC, ROWS)                                      \
  {                                                               \
    const float4* g4 = (const float4*)(SRC);                      \
    _Pragma("unroll") for (int i = 0; i < (ROWS) / 16; ++i) {     \
      const int e = tid + i * 512;                                \
      const int r = e >> 5, c = (e & 31) << 2;                    \
      *(float4*)(s_pool + r * PSTRIDE + c) = g4[e];               \
    }                                                             \
    __syncthreads();                                              \
  }

  STAGE_MAT(Uz, 128)
  if (team == 0) {
#pragma unroll
    for (int j = 0; j < 64; ++j)
      wcol[j] = packh2(s_pool[(2 * j) * PSTRIDE + uu], s_pool[(2 * j + 1) * PSTRIDE + uu]);
  }
  __syncthreads();
  STAGE_MAT(Ur, 128)
  if (team == 1) {
#pragma unroll
    for (int j = 0; j < 64; ++j)
      wcol[j] = packh2(s_pool[(2 * j) * PSTRIDE + uu], s_pool[(2 * j + 1) * PSTRIDE + uu]);
  }
  __syncthreads();
  STAGE_MAT(Uh, 128)
  if (team == 2) {
#pragma unroll
    for (int j = 0; j < 64; ++j)
      wcol[j] = packh2(s_pool[(2 * j) * PSTRIDE + uu], s_pool[(2 * j + 1) * PSTRIDE + uu]);
  }
  __syncthreads();
  STAGE_MAT(Wz, 64)
  if (team == 3) {
#pragma unroll
    for (int j = 0; j < 32; ++j)
      wcol[j] = packh2(s_pool[(2 * j) * PSTRIDE + uu], s_pool[(2 * j + 1) * PSTRIDE + uu]);
  }
  __syncthreads();
  STAGE_MAT(Wr, 64)
  if (team == 3) {
#pragma unroll
    for (int j = 0; j < 32; ++j)
      wcol[32 + j] = packh2(s_pool[(2 * j) * PSTRIDE + uu], s_pool[(2 * j + 1) * PSTRIDE + uu]);
  }
  __syncthreads();
  STAGE_MAT(Wh, 64)
  if (team == 3) {
#pragma unroll
    for (int j = 0; j < 32; ++j)
      wcol[64 + j] = packh2(s_pool[(2 * j) * PSTRIDE + uu], s_pool[(2 * j + 1) * PSTRIDE + uu]);
  }
  __syncthreads();

  // per-team preloads
  float bzu = 0.f, bru = 0.f, bhu = 0.f;   // X-team biases
  float negg = 0.f, hd_reg = 0.f;          // H-team decay + fp32 hidden state
  if (team == 3) { bzu = bz[uu]; bru = br[uu]; bhu = bh[uu]; }
  if (team == 2) { negg = -fmaxf(ghd[uu], 0.0f); }
  if (tid < U_) s_hd16[tid] = 0;           // h0 = 0

  const uint4* const hd4 = (const uint4*)s_hd16;
  const uint4* const rh4 = (const uint4*)s_rh16;

  for (int t0 = 0; t0 < T_; t0 += 32) {
    // ---- stage chunk: dt + decayed x (fp16) ----
    if (tid < 33) {
      const int t = t0 + tid;
      s_dt[tid] = (t < T_) ? delta_t[b * T_ + t] : 0.0f;
    }
    {
      const int idx0 = tid * 4;          // halves; [32][64]
      const int tt = idx0 >> 6, f0 = idx0 & 63;
      const float dtv = delta_t[b * T_ + t0 + tt];
      const float4 xv  = *(const float4*)(x  + (size_t)(b * T_ + t0 + tt) * F_ + f0);
      const float4 mv  = *(const float4*)(m  + (size_t)(b * T_ + t0 + tt) * F_ + f0);
      const float4 gv  = *(const float4*)(gxd + f0);
      const float4 miv = *(const float4*)(mi  + f0);
      float gx, d0, d1, d2, d3;
      gx = __expf(-fmaxf(gv.x, 0.0f) * dtv);
      d0 = mv.x * xv.x + (1.0f - mv.x) * (gx * xv.x + (1.0f - gx) * miv.x);
      gx = __expf(-fmaxf(gv.y, 0.0f) * dtv);
      d1 = mv.y * xv.y + (1.0f - mv.y) * (gx * xv.y + (1.0f - gx) * miv.y);
      gx = __expf(-fmaxf(gv.z, 0.0f) * dtv);
      d2 = mv.z * xv.z + (1.0f - mv.z) * (gx * xv.z + (1.0f - gx) * miv.z);
      gx = __expf(-fmaxf(gv.w, 0.0f) * dtv);
      d3 = mv.w * xv.w + (1.0f - mv.w) * (gx * xv.w + (1.0f - gx) * miv.w);
      uint2 px; px.x = packh2(d0, d1); px.y = packh2(d2, d3);
      *(uint2*)(s_x16h + idx0) = px;
    }
    __syncthreads();

    // ---- chunk prologue: X computes ax[0] (all 3 gates) for tc=0 ----
    if (team == 3) {
      const uint4* xp = (const uint4*)s_x16h;
      float a0 = bzu, a1 = bru, a2 = bhu;
#pragma unroll
      for (int q = 0; q < 8; ++q) {
        const uint4 xq = xp[q];
        a0 = fdot2(xq.x, wcol[4*q+0], a0); a0 = fdot2(xq.y, wcol[4*q+1], a0);
        a0 = fdot2(xq.z, wcol[4*q+2], a0); a0 = fdot2(xq.w, wcol[4*q+3], a0);
        a1 = fdot2(xq.x, wcol[32+4*q+0], a1); a1 = fdot2(xq.y, wcol[32+4*q+1], a1);
        a1 = fdot2(xq.z, wcol[32+4*q+2], a1); a1 = fdot2(xq.w, wcol[32+4*q+3], a1);
        a2 = fdot2(xq.x, wcol[64+4*q+0], a2); a2 = fdot2(xq.y, wcol[64+4*q+1], a2);
        a2 = fdot2(xq.z, wcol[64+4*q+2], a2); a2 = fdot2(xq.w, wcol[64+4*q+3], a2);
      }
      s_ax[0 * 384 + 0 * 128 + uu] = a0;
      s_ax[0 * 384 + 1 * 128 + uu] = a1;
      s_ax[0 * 384 + 2 * 128 + uu] = a2;
    }
    __syncthreads();

#pragma unroll 2
    for (int tc = 0; tc < 32; ++tc) {
      const int cur = tc & 1, nxt = cur ^ 1;

      // ================= PHASE B =================
      if (team == 0) {              // ---- z gate ----
        float a0 = s_ax[cur * 384 + uu], a1 = 0.f, a2 = 0.f, a3 = 0.f;
#pragma unroll
        for (int q = 0; q < 4; ++q) {
          const uint4 h0 = hd4[4*q+0], h1 = hd4[4*q+1], h2 = hd4[4*q+2], h3 = hd4[4*q+3];
          a0 = fdot2(h0.x, wcol[16*q+0], a0);  a0 = fdot2(h0.y, wcol[16*q+1], a0);
          a0 = fdot2(h0.z, wcol[16*q+2], a0);  a0 = fdot2(h0.w, wcol[16*q+3], a0);
          a1 = fdot2(h1.x, wcol[16*q+4], a1);  a1 = fdot2(h1.y, wcol[16*q+5], a1);
          a1 = fdot2(h1.z, wcol[16*q+6], a1);  a1 = fdot2(h1.w, wcol[16*q+7], a1);
          a2 = fdot2(h2.x, wcol[16*q+8], a2);  a2 = fdot2(h2.y, wcol[16*q+9], a2);
          a2 = fdot2(h2.z, wcol[16*q+10], a2); a2 = fdot2(h2.w, wcol[16*q+11], a2);
          a3 = fdot2(h3.x, wcol[16*q+12], a3); a3 = fdot2(h3.y, wcol[16*q+13], a3);
          a3 = fdot2(h3.z, wcol[16*q+14], a3); a3 = fdot2(h3.w, wcol[16*q+15], a3);
        }
        s_zf[uu] = fast_sig((a0 + a1) + (a2 + a3));
      } else if (team == 1) {       // ---- r gate ----
        float a0 = s_ax[cur * 384 + 128 + uu], a1 = 0.f, a2 = 0.f, a3 = 0.f;
#pragma unroll
        for (int q = 0; q < 4; ++q) {
          const uint4 h0 = hd4[4*q+0], h1 = hd4[4*q+1], h2 = hd4[4*q+2], h3 = hd4[4*q+3];
          a0 = fdot2(h0.x, wcol[16*q+0], a0);  a0 = fdot2(h0.y, wcol[16*q+1], a0);
          a0 = fdot2(h0.z, wcol[16*q+2], a0);  a0 = fdot2(h0.w, wcol[16*q+3], a0);
          a1 = fdot2(h1.x, wcol[16*q+4], a1);  a1 = fdot2(h1.y, wcol[16*q+5], a1);
          a1 = fdot2(h1.z, wcol[16*q+6], a1);  a1 = fdot2(h1.w, wcol[16*q+7], a1);
          a2 = fdot2(h2.x, wcol[16*q+8], a2);  a2 = fdot2(h2.y, wcol[16*q+9], a2);
          a2 = fdot2(h2.z, wcol[16*q+10], a2); a2 = fdot2(h2.w, wcol[16*q+11], a2);
          a3 = fdot2(h3.x, wcol[16*q+12], a3); a3 = fdot2(h3.y, wcol[16*q+13], a3);
          a3 = fdot2(h3.z, wcol[16*q+14], a3); a3 = fdot2(h3.w, wcol[16*q+15], a3);
        }
        const float r = fast_sig((a0 + a1) + (a2 + a3));
        const float hdv = (float)((const _Float16*)s_hd16)[uu];
        ((_Float16*)s_rh16)[uu] = (_Float16)(r * hdv);
      } else if (team == 3) {       // ---- x-proj, z gate for tc+1 ----
        if (tc < 31) {
          const uint4* xp = (const uint4*)(s_x16h + (tc + 1) * 64);
          float a0 = bzu, a1 = 0.f;
#pragma unroll
          for (int q = 0; q < 4; ++q) {
            const uint4 xq = xp[2*q], xq2 = xp[2*q+1];
            a0 = fdot2(xq.x,  wcol[8*q+0], a0); a0 = fdot2(xq.y,  wcol[8*q+1], a0);
            a0 = fdot2(xq.z,  wcol[8*q+2], a0); a0 = fdot2(xq.w,  wcol[8*q+3], a0);
            a1 = fdot2(xq2.x, wcol[8*q+4], a1); a1 = fdot2(xq2.y, wcol[8*q+5], a1);
            a1 = fdot2(xq2.z, wcol[8*q+6], a1); a1 = fdot2(xq2.w, wcol[8*q+7], a1);
          }
          s_ax[nxt * 384 + uu] = a0 + a1;
        }
      }
      __syncthreads();

      // ================= PHASE C =================
      if (team == 2) {              // ---- candidate + update ----
        float a0 = s_ax[cur * 384 + 256 + uu], a1 = 0.f, a2 = 0.f, a3 = 0.f;
#pragma unroll
        for (int q = 0; q < 4; ++q) {
          const uint4 r0 = rh4[4*q+0], r1 = rh4[4*q+1], r2 = rh4[4*q+2], r3 = rh4[4*q+3];
          a0 = fdot2(r0.x, wcol[16*q+0], a0);  a0 = fdot2(r0.y, wcol[16*q+1], a0);
          a0 = fdot2(r0.z, wcol[16*q+2], a0);  a0 = fdot2(r0.w, wcol[16*q+3], a0);
          a1 = fdot2(r1.x, wcol[16*q+4], a1);  a1 = fdot2(r1.y, wcol[16*q+5], a1);
          a1 = fdot2(r1.z, wcol[16*q+6], a1);  a1 = fdot2(r1.w, wcol[16*q+7], a1);
          a2 = fdot2(r2.x, wcol[16*q+8], a2);  a2 = fdot2(r2.y, wcol[16*q+9], a2);
          a2 = fdot2(r2.z, wcol[16*q+10], a2); a2 = fdot2(r2.w, wcol[16*q+11], a2);
          a3 = fdot2(r3.x, wcol[16*q+12], a3); a3 = fdot2(r3.y, wcol[16*q+13], a3);
          a3 = fdot2(r3.z, wcol[16*q+14], a3); a3 = fdot2(r3.w, wcol[16*q+15], a3);
        }
        const float hh = fast_tanh((a0 + a1) + (a2 + a3));
        const float z  = s_zf[uu];
        const float hn = fmaf(z, hh - hd_reg, hd_reg);
        out[(size_t)(b * T_ + t0 + tc) * U_ + uu] = hn;
        hd_reg = hn * __expf(negg * s_dt[tc + 1]);
        ((_Float16*)s_hd16)[uu] = (_Float16)hd_reg;
      } else if (team == 3) {       // ---- x-proj, r+h gates for tc+1 ----
        if (tc < 31) {
          const uint4* xp = (const uint4*)(s_x16h + (tc + 1) * 64);
          float a1 = bru, a2 = bhu;
#pragma unroll
          for (int q = 0; q < 8; ++q) {
            const uint4 xq = xp[q];
            a1 = fdot2(xq.x, wcol[32+4*q+0], a1); a1 = fdot2(xq.y, wcol[32+4*q+1], a1);
            a1 = fdot2(xq.z, wcol[32+4*q+2], a1); a1 = fdot2(xq.w, wcol[32+4*q+3], a1);
            a2 = fdot2(xq.x, wcol[64+4*q+0], a2); a2 = fdot2(xq.y, wcol[64+4*q+1], a2);
            a2 = fdot2(xq.z, wcol[64+4*q+2], a2); a2 = fdot2(xq.w, wcol[64+4*q+3], a2);
          }
          s_ax[nxt * 384 + 128 + uu] = a1;
          s_ax[nxt * 384 + 256 + uu] = a2;
        }
      }
      __syncthreads();
    }
  }
}

extern "C" void kernel_launch(void* const* d_in, const int* in_sizes, int n_in,
                              void* d_out, int out_size, void* d_ws, size_t ws_size,
                              hipStream_t stream) {
  const float* x   = (const float*)d_in[0];
  const float* m   = (const float*)d_in[1];
  const float* dt  = (const float*)d_in[2];
  const float* Wz  = (const float*)d_in[3];
  const float* Uz  = (const float*)d_in[4];
  const float* bz  = (const float*)d_in[5];
  const float* Wr  = (const float*)d_in[6];
  const float* Ur  = (const float*)d_in[7];
  const float* br  = (const float*)d_in[8];
  const float* Wh  = (const float*)d_in[9];
  const float* Uh  = (const float*)d_in[10];
  const float* bh  = (const float*)d_in[11];
  const float* gxd = (const float*)d_in[12];
  const float* ghd = (const float*)d_in[13];
  const float* mi  = (const float*)d_in[14];

  grud_kernel<<<dim3(B_), dim3(512), 0, stream>>>(
      x, m, dt, Wz, Uz, bz, Wr, Ur, br, Wh, Uh, bh, gxd, ghd, mi, (float*)d_out);
}